// Round 2
// baseline (4154.852 us; speedup 1.0000x reference)
//
#include <hip/hip_runtime.h>
#include <cmath>

// Batched log(SPD 64x64) via one-sided Jacobi.
// One wave (64 lanes) per matrix; lane k owns column k of F (starts = X).
// Right Jacobi rotations orthogonalize columns: F -> X*J = Q*diag(lambda).
// Then log(X) = U diag(log lambda) U^T with u_k = f_k/||f_k||, lambda_k = ||f_k||
// (unique SPD root: X^2 = Q diag(lambda^2) Q^T and X SPD => X = Q diag(lambda) Q^T).
// No eigenvector accumulation needed.

#define NMAT_PER_BLOCK 4
#define MAXSWEEP 18
#define JTOL 1e-5f
#define TSTRIDE 68  // floats; 68%32==4 -> spreads banks, 16B-aligned rows

__global__ __launch_bounds__(256, 2)
void logeig_kernel(const float* __restrict__ X, float* __restrict__ Out, int B)
{
    const int wave = threadIdx.x >> 6;
    const int lane = threadIdx.x & 63;
    long b = (long)blockIdx.x * NMAT_PER_BLOCK + wave;
    if (b >= B) b = B - 1;  // duplicate work (identical writes) if ragged

    __shared__ float Tlds[NMAT_PER_BLOCK][64 * TSTRIDE];
    __shared__ float wlds[NMAT_PER_BLOCK][64];

    const float* Xb = X + b * 4096;
    float*       Ob = Out + b * 4096;

    // Column `lane` of X == row `lane` (symmetric) -> contiguous load.
    float f[64];
#pragma unroll
    for (int i = 0; i < 16; ++i) {
        const float4 v = reinterpret_cast<const float4*>(Xb + lane * 64)[i];
        f[4*i+0] = v.x; f[4*i+1] = v.y; f[4*i+2] = v.z; f[4*i+3] = v.w;
    }

    // own squared column norm (tracked incrementally across rotations)
    float app = 0.f;
#pragma unroll
    for (int j = 0; j < 64; ++j) app = fmaf(f[j], f[j], app);

    for (int sweep = 0; sweep < MAXSWEEP; ++sweep) {
        bool any_rot = false;
        for (int r = 1; r < 64; ++r) {
            // XOR tournament: pair (i,j) meets exactly once per sweep at r=i^j
            const int partner = lane ^ r;
            const int pa = partner << 2;

            // fetch partner's column (64 dwords cross-lane)
            float tmp[64];
#pragma unroll
            for (int j = 0; j < 64; ++j)
                tmp[j] = __int_as_float(__builtin_amdgcn_ds_bpermute(pa, __float_as_int(f[j])));

            const float aqq = __int_as_float(__builtin_amdgcn_ds_bpermute(pa, __float_as_int(app)));

            float apq = 0.f;
#pragma unroll
            for (int j = 0; j < 64; ++j) apq = fmaf(f[j], tmp[j], apq);

            // bit-identical across the pair: fmaf(a,b,c)==fmaf(b,a,c), same j order
            const bool rot = fabsf(apq) > JTOL * sqrtf(app * aqq);
            any_rot |= rot;

            if (__any(rot)) {
                // canonical orientation: p = min-lane, q = max-lane.
                // Both lanes compute IDENTICAL tau,t0,c0,s0; min-lane applies +s0,
                // max-lane -s0 (exact negation -> consistent pair update, robust
                // to app==aqq ties).
                const bool  isp = lane < partner;
                const float App = isp ? app : aqq;
                const float Aqq = isp ? aqq : app;
                const float tau = (Aqq - App) / (2.f * apq);
                const float t0  = copysignf(1.f, tau) / (fabsf(tau) + sqrtf(fmaf(tau, tau, 1.f)));
                const float c0  = rsqrtf(fmaf(t0, t0, 1.f));
                const float s0  = t0 * c0;
                const float tl  = rot ? (isp ? t0 : -t0) : 0.f;
                const float c   = rot ? c0 : 1.f;
                const float sl  = rot ? (isp ? s0 : -s0) : 0.f;
#pragma unroll
                for (int j = 0; j < 64; ++j)
                    f[j] = fmaf(-sl, tmp[j], c * f[j]);
                // exact 2x2 identity: new own diag = own - t_lane*apq
                app = fmaf(-tl, apq, app);
            }
        }
        if (!__any(any_rot)) break;
    }

    // ---- epilogue: O = U diag(w) U^T, w = log(lambda) ----
    float nrm2 = 0.f;
#pragma unroll
    for (int j = 0; j < 64; ++j) nrm2 = fmaf(f[j], f[j], nrm2);
    const float wk  = 0.5f * logf(nrm2);   // log(||f||) = log(lambda)
    const float inv = rsqrtf(nrm2);

    float* T = Tlds[wave];
#pragma unroll
    for (int i = 0; i < 16; ++i) {
        float4 v;
        v.x = f[4*i+0] * inv; v.y = f[4*i+1] * inv;
        v.z = f[4*i+2] * inv; v.w = f[4*i+3] * inv;
        reinterpret_cast<float4*>(T + lane * TSTRIDE)[i] = v;  // row `lane` = u_lane
    }
    wlds[wave][lane] = wk;
    __syncthreads();  // per-wave private LDS regions; sync is belt-and-braces

    // each lane computes an 8x8 tile of O; O[a][c] = sum_k w_k * U[k][a] * U[k][c]
    const int la = lane >> 3, lb = lane & 7;
    float acc[8][8];
#pragma unroll
    for (int r0 = 0; r0 < 8; ++r0)
#pragma unroll
        for (int c0 = 0; c0 < 8; ++c0) acc[r0][c0] = 0.f;

    const float* wv = wlds[wave];
#pragma unroll 4
    for (int k = 0; k < 64; ++k) {
        const float wkk = wv[k];
        const float* row = T + k * TSTRIDE;
        const float4 p0 = *reinterpret_cast<const float4*>(row + la * 8);
        const float4 p1 = *reinterpret_cast<const float4*>(row + la * 8 + 4);
        const float4 u0 = *reinterpret_cast<const float4*>(row + lb * 8);
        const float4 u1 = *reinterpret_cast<const float4*>(row + lb * 8 + 4);
        const float pr[8] = { p0.x*wkk, p0.y*wkk, p0.z*wkk, p0.w*wkk,
                              p1.x*wkk, p1.y*wkk, p1.z*wkk, p1.w*wkk };
        const float uc[8] = { u0.x, u0.y, u0.z, u0.w, u1.x, u1.y, u1.z, u1.w };
#pragma unroll
        for (int r0 = 0; r0 < 8; ++r0)
#pragma unroll
            for (int c0 = 0; c0 < 8; ++c0)
                acc[r0][c0] = fmaf(pr[r0], uc[c0], acc[r0][c0]);
    }

#pragma unroll
    for (int r0 = 0; r0 < 8; ++r0) {
        float* dst = Ob + (la * 8 + r0) * 64 + lb * 8;
        float4 o0 = { acc[r0][0], acc[r0][1], acc[r0][2], acc[r0][3] };
        float4 o1 = { acc[r0][4], acc[r0][5], acc[r0][6], acc[r0][7] };
        reinterpret_cast<float4*>(dst)[0] = o0;
        reinterpret_cast<float4*>(dst)[1] = o1;
    }
}

extern "C" void kernel_launch(void* const* d_in, const int* in_sizes, int n_in,
                              void* d_out, int out_size, void* d_ws, size_t ws_size,
                              hipStream_t stream)
{
    const float* Xp = (const float*)d_in[0];
    float* Op = (float*)d_out;
    const int B = in_sizes[0] / 4096;                 // 8192
    const int grid = (B + NMAT_PER_BLOCK - 1) / NMAT_PER_BLOCK;  // 2048
    logeig_kernel<<<grid, 256, 0, stream>>>(Xp, Op, B);
}

// Round 3
// 4144.969 us; speedup vs baseline: 1.0024x; 1.0024x over previous
//
#include <hip/hip_runtime.h>
#include <cmath>

// Batched log(SPD 64x64) via one-sided Jacobi.
// One wave (64 lanes) per matrix; lane k owns column k of F (starts = X).
// Right Jacobi rotations orthogonalize columns: F -> X*J = Q*diag(lambda).
// log(X) = U diag(log lambda) U^T, u_k = f_k/||f_k||, lambda_k = ||f_k||.
//
// r3 changes vs r2 (latency-bound at ~3100 cyc/round, ideal ~450):
//  - partner column pinned in VGPRs via empty-asm barrier (compiler was
//    rematerializing the 64 ds_bpermutes for the update pass: VGPR=88 < 128)
//  - dot product: 4 packed float2 accumulators instead of a serial 64-FMA chain
//  - float2 ext-vector math for dot+update (v_pk_fma_f32 on CDNA)

#define NMAT_PER_BLOCK 4
#define MAXSWEEP 18
#define JTOL 1e-5f
#define TSTRIDE 68  // floats; measured 0 bank conflicts in epilogue

typedef float f32x2 __attribute__((ext_vector_type(2)));

__global__ __launch_bounds__(256, 2)
void logeig_kernel(const float* __restrict__ X, float* __restrict__ Out, int B)
{
    const int wave = threadIdx.x >> 6;
    const int lane = threadIdx.x & 63;
    long b = (long)blockIdx.x * NMAT_PER_BLOCK + wave;
    if (b >= B) b = B - 1;

    __shared__ float Tlds[NMAT_PER_BLOCK][64 * TSTRIDE];
    __shared__ float wlds[NMAT_PER_BLOCK][64];

    const float* Xb = X + b * 4096;
    float*       Ob = Out + b * 4096;

    // Column `lane` of X == row `lane` (symmetric) -> contiguous load.
    f32x2 fv[32];
#pragma unroll
    for (int i = 0; i < 16; ++i) {
        const float4 v = reinterpret_cast<const float4*>(Xb + lane * 64)[i];
        fv[2*i+0] = f32x2{v.x, v.y};
        fv[2*i+1] = f32x2{v.z, v.w};
    }

    // own squared column norm (tracked incrementally across rotations)
    float app;
    {
        f32x2 a0 = {0.f,0.f}, a1 = {0.f,0.f}, a2 = {0.f,0.f}, a3 = {0.f,0.f};
#pragma unroll
        for (int i = 0; i < 32; i += 4) {
            a0 = __builtin_elementwise_fma(fv[i+0], fv[i+0], a0);
            a1 = __builtin_elementwise_fma(fv[i+1], fv[i+1], a1);
            a2 = __builtin_elementwise_fma(fv[i+2], fv[i+2], a2);
            a3 = __builtin_elementwise_fma(fv[i+3], fv[i+3], a3);
        }
        const f32x2 at = (a0 + a1) + (a2 + a3);
        app = at.x + at.y;
    }

    for (int sweep = 0; sweep < MAXSWEEP; ++sweep) {
        bool any_rot = false;
        for (int r = 1; r < 64; ++r) {
            // XOR tournament: pair (i,j) meets exactly once per sweep at r=i^j
            const int partner = lane ^ r;
            const int pa = partner << 2;

            // fetch partner's column (64 dwords cross-lane), PIN in registers
            f32x2 tv[32];
#pragma unroll
            for (int i = 0; i < 32; ++i) {
                const int lo = __builtin_amdgcn_ds_bpermute(pa, __float_as_int(fv[i].x));
                const int hi = __builtin_amdgcn_ds_bpermute(pa, __float_as_int(fv[i].y));
                tv[i] = f32x2{__int_as_float(lo), __int_as_float(hi)};
            }
            const float aqq = __int_as_float(__builtin_amdgcn_ds_bpermute(pa, __float_as_int(app)));
#pragma unroll
            for (int i = 0; i < 32; ++i)
                asm("" : "+v"(tv[i]));   // defeat ds_bpermute rematerialization

            // apq: 4 packed accumulators; structure identical on both lanes of a
            // pair and multiply is commutative -> bit-identical apq across pair.
            float apq;
            {
                f32x2 a0 = {0.f,0.f}, a1 = {0.f,0.f}, a2 = {0.f,0.f}, a3 = {0.f,0.f};
#pragma unroll
                for (int i = 0; i < 32; i += 4) {
                    a0 = __builtin_elementwise_fma(fv[i+0], tv[i+0], a0);
                    a1 = __builtin_elementwise_fma(fv[i+1], tv[i+1], a1);
                    a2 = __builtin_elementwise_fma(fv[i+2], tv[i+2], a2);
                    a3 = __builtin_elementwise_fma(fv[i+3], tv[i+3], a3);
                }
                const f32x2 at = (a0 + a1) + (a2 + a3);
                apq = at.x + at.y;
            }

            const bool rot = fabsf(apq) > JTOL * sqrtf(app * aqq);
            any_rot |= rot;

            if (__any(rot)) {
                // canonical orientation: p = min-lane, q = max-lane. Both lanes
                // compute IDENTICAL tau,t0,c0,s0; min-lane applies +s0, max-lane
                // -s0 (exact negation -> consistent pair update, tie-robust).
                const bool  isp = lane < partner;
                const float App = isp ? app : aqq;
                const float Aqq = isp ? aqq : app;
                const float tau = (Aqq - App) / (2.f * apq);
                const float t0  = copysignf(1.f, tau) / (fabsf(tau) + sqrtf(fmaf(tau, tau, 1.f)));
                const float c0  = rsqrtf(fmaf(t0, t0, 1.f));
                const float s0  = t0 * c0;
                const float tl  = rot ? (isp ? t0 : -t0) : 0.f;
                const float c   = rot ? c0 : 1.f;
                const float sl  = rot ? (isp ? s0 : -s0) : 0.f;

                const f32x2 c2  = {c, c};
                const f32x2 ns2 = {-sl, -sl};
#pragma unroll
                for (int i = 0; i < 32; ++i)
                    fv[i] = __builtin_elementwise_fma(ns2, tv[i], c2 * fv[i]);
                // exact 2x2 identity: new own diag = own - t_lane*apq
                app = fmaf(-tl, apq, app);
            }
        }
        if (!__any(any_rot)) break;
    }

    // ---- epilogue: O = U diag(w) U^T, w = log(lambda) ----
    float nrm2;
    {
        f32x2 a0 = {0.f,0.f}, a1 = {0.f,0.f}, a2 = {0.f,0.f}, a3 = {0.f,0.f};
#pragma unroll
        for (int i = 0; i < 32; i += 4) {
            a0 = __builtin_elementwise_fma(fv[i+0], fv[i+0], a0);
            a1 = __builtin_elementwise_fma(fv[i+1], fv[i+1], a1);
            a2 = __builtin_elementwise_fma(fv[i+2], fv[i+2], a2);
            a3 = __builtin_elementwise_fma(fv[i+3], fv[i+3], a3);
        }
        const f32x2 at = (a0 + a1) + (a2 + a3);
        nrm2 = at.x + at.y;
    }
    const float wk  = 0.5f * logf(nrm2);   // log(||f||) = log(lambda)
    const float inv = rsqrtf(nrm2);

    float* T = Tlds[wave];
#pragma unroll
    for (int i = 0; i < 16; ++i) {
        float4 v;
        v.x = fv[2*i+0].x * inv; v.y = fv[2*i+0].y * inv;
        v.z = fv[2*i+1].x * inv; v.w = fv[2*i+1].y * inv;
        reinterpret_cast<float4*>(T + lane * TSTRIDE)[i] = v;  // row `lane` = u_lane
    }
    wlds[wave][lane] = wk;
    __syncthreads();

    // each lane computes an 8x8 tile of O; O[a][c] = sum_k w_k * U[k][a] * U[k][c]
    const int la = lane >> 3, lb = lane & 7;
    float acc[8][8];
#pragma unroll
    for (int r0 = 0; r0 < 8; ++r0)
#pragma unroll
        for (int c0 = 0; c0 < 8; ++c0) acc[r0][c0] = 0.f;

    const float* wv = wlds[wave];
#pragma unroll 4
    for (int k = 0; k < 64; ++k) {
        const float wkk = wv[k];
        const float* row = T + k * TSTRIDE;
        const float4 p0 = *reinterpret_cast<const float4*>(row + la * 8);
        const float4 p1 = *reinterpret_cast<const float4*>(row + la * 8 + 4);
        const float4 u0 = *reinterpret_cast<const float4*>(row + lb * 8);
        const float4 u1 = *reinterpret_cast<const float4*>(row + lb * 8 + 4);
        const float pr[8] = { p0.x*wkk, p0.y*wkk, p0.z*wkk, p0.w*wkk,
                              p1.x*wkk, p1.y*wkk, p1.z*wkk, p1.w*wkk };
        const float uc[8] = { u0.x, u0.y, u0.z, u0.w, u1.x, u1.y, u1.z, u1.w };
#pragma unroll
        for (int r0 = 0; r0 < 8; ++r0)
#pragma unroll
            for (int c0 = 0; c0 < 8; ++c0)
                acc[r0][c0] = fmaf(pr[r0], uc[c0], acc[r0][c0]);
    }

#pragma unroll
    for (int r0 = 0; r0 < 8; ++r0) {
        float* dst = Ob + (la * 8 + r0) * 64 + lb * 8;
        float4 o0 = { acc[r0][0], acc[r0][1], acc[r0][2], acc[r0][3] };
        float4 o1 = { acc[r0][4], acc[r0][5], acc[r0][6], acc[r0][7] };
        reinterpret_cast<float4*>(dst)[0] = o0;
        reinterpret_cast<float4*>(dst)[1] = o1;
    }
}

extern "C" void kernel_launch(void* const* d_in, const int* in_sizes, int n_in,
                              void* d_out, int out_size, void* d_ws, size_t ws_size,
                              hipStream_t stream)
{
    const float* Xp = (const float*)d_in[0];
    float* Op = (float*)d_out;
    const int B = in_sizes[0] / 4096;                 // 8192
    const int grid = (B + NMAT_PER_BLOCK - 1) / NMAT_PER_BLOCK;  // 2048
    logeig_kernel<<<grid, 256, 0, stream>>>(Xp, Op, B);
}

// Round 4
// 3201.610 us; speedup vs baseline: 1.2977x; 1.2947x over previous
//
#include <hip/hip_runtime.h>
#include <cmath>

// Batched log(SPD 64x64) via one-sided Jacobi, LDS-resident columns.
// One wave per matrix; lane k owns column k of F in REGISTERS and mirrors it
// in LDS. Partner-column fetch = 16 ds_read_b128 (16B/lane/instr) instead of
// 64 ds_bpermute (4B/lane/instr) -> ~4x fewer DS instructions on the
// DS-pipe-bound inner loop (r3 counters: DS-issue-bound at ~2200 cyc/round).
// Rotating lanes write their updated column back (16 ds_write_b128).
// Within-wave DS ops execute in program order -> write(t) visible to read(t+1).
//
// Exit rule decoupled from rotation rule: rotate if |apq| > JTOL*sqrt(app*aqq),
// exit when a full sweep saw nothing above XTOL (r3 timing showed the JTOL
// exit never fired; sweeps 9-18 were pure fetch+dot).

#define NMAT_PER_BLOCK 4
#define MAXSWEEP 18
#define JTOL 1e-5f
#define XTOL 5e-5f
#define TSTRIDE 68  // floats = 17 float4s (odd) -> spread bank groups

typedef float f32x2 __attribute__((ext_vector_type(2)));

__global__ __launch_bounds__(256, 2)
void logeig_kernel(const float* __restrict__ X, float* __restrict__ Out, int B)
{
    const int wave = threadIdx.x >> 6;
    const int lane = threadIdx.x & 63;
    long b = (long)blockIdx.x * NMAT_PER_BLOCK + wave;
    if (b >= B) b = B - 1;

    __shared__ float Tlds[NMAT_PER_BLOCK][64 * TSTRIDE];
    __shared__ float wlds[NMAT_PER_BLOCK][64];

    const float* Xb = X + b * 4096;
    float*       Ob = Out + b * 4096;
    float*       T  = Tlds[wave];
    float4*      myrow = reinterpret_cast<float4*>(T + lane * TSTRIDE);

    // Column `lane` of X == row `lane` (symmetric) -> contiguous load.
    f32x2 fv[32];
#pragma unroll
    for (int i = 0; i < 16; ++i) {
        const float4 v = reinterpret_cast<const float4*>(Xb + lane * 64)[i];
        fv[2*i+0] = f32x2{v.x, v.y};
        fv[2*i+1] = f32x2{v.z, v.w};
        myrow[i] = v;                       // mirror column into LDS
    }
    __builtin_amdgcn_wave_barrier();

    // own squared column norm (tracked incrementally across rotations)
    float app;
    {
        f32x2 a0 = {0.f,0.f}, a1 = {0.f,0.f}, a2 = {0.f,0.f}, a3 = {0.f,0.f};
#pragma unroll
        for (int i = 0; i < 32; i += 4) {
            a0 = __builtin_elementwise_fma(fv[i+0], fv[i+0], a0);
            a1 = __builtin_elementwise_fma(fv[i+1], fv[i+1], a1);
            a2 = __builtin_elementwise_fma(fv[i+2], fv[i+2], a2);
            a3 = __builtin_elementwise_fma(fv[i+3], fv[i+3], a3);
        }
        const f32x2 at = (a0 + a1) + (a2 + a3);
        app = at.x + at.y;
    }

    for (int sweep = 0; sweep < MAXSWEEP; ++sweep) {
        bool big = false;
        for (int r = 1; r < 64; ++r) {
            // XOR tournament: pair (i,j) meets exactly once per sweep at r=i^j
            const int partner = lane ^ r;

            // partner's squared norm (scalar, overlaps with column reads)
            const float aqq = __int_as_float(
                __builtin_amdgcn_ds_bpermute(partner << 2, __float_as_int(app)));

            // fetch partner's column: 16 x ds_read_b128
            const float4* pc = reinterpret_cast<const float4*>(T + partner * TSTRIDE);
            f32x2 tv[32];
#pragma unroll
            for (int i = 0; i < 16; ++i) {
                const float4 v = pc[i];
                tv[2*i+0] = f32x2{v.x, v.y};
                tv[2*i+1] = f32x2{v.z, v.w};
            }
#pragma unroll
            for (int i = 0; i < 32; ++i)
                asm volatile("" : "+v"(tv[i]));   // pin: no re-load for update pass

            // apq: commutative products, identical order on both lanes of the
            // pair -> bit-identical apq -> identical rot decision & angles.
            float apq;
            {
                f32x2 a0 = {0.f,0.f}, a1 = {0.f,0.f}, a2 = {0.f,0.f}, a3 = {0.f,0.f};
#pragma unroll
                for (int i = 0; i < 32; i += 4) {
                    a0 = __builtin_elementwise_fma(fv[i+0], tv[i+0], a0);
                    a1 = __builtin_elementwise_fma(fv[i+1], tv[i+1], a1);
                    a2 = __builtin_elementwise_fma(fv[i+2], tv[i+2], a2);
                    a3 = __builtin_elementwise_fma(fv[i+3], tv[i+3], a3);
                }
                const f32x2 at = (a0 + a1) + (a2 + a3);
                apq = at.x + at.y;
            }

            const float thr = sqrtf(app * aqq);
            const bool rot = fabsf(apq) > JTOL * thr;
            big = big || (fabsf(apq) > XTOL * thr);

            if (__any(rot)) {
                // canonical orientation: p = min-lane, q = max-lane. Both lanes
                // compute IDENTICAL tau,t0,c0,s0; min-lane applies +s0, max-lane
                // -s0 (exact negation -> consistent pair update, tie-robust).
                const bool  isp = lane < partner;
                const float App = isp ? app : aqq;
                const float Aqq = isp ? aqq : app;
                const float tau = (Aqq - App) / (2.f * apq);
                const float t0  = copysignf(1.f, tau) / (fabsf(tau) + sqrtf(fmaf(tau, tau, 1.f)));
                const float c0  = rsqrtf(fmaf(t0, t0, 1.f));
                const float s0  = t0 * c0;
                const float tl  = rot ? (isp ? t0 : -t0) : 0.f;
                const float c   = rot ? c0 : 1.f;
                const float sl  = rot ? (isp ? s0 : -s0) : 0.f;

                const f32x2 c2  = {c, c};
                const f32x2 ns2 = {-sl, -sl};
#pragma unroll
                for (int i = 0; i < 32; ++i)
                    fv[i] = __builtin_elementwise_fma(ns2, tv[i], c2 * fv[i]);
                // exact 2x2 identity: new own diag = own - t_lane*apq
                app = fmaf(-tl, apq, app);

                if (rot) {
                    // write updated column back to LDS (16 x ds_write_b128)
#pragma unroll
                    for (int i = 0; i < 16; ++i)
                        myrow[i] = float4{fv[2*i+0].x, fv[2*i+0].y,
                                          fv[2*i+1].x, fv[2*i+1].y};
                }
            }
            __builtin_amdgcn_wave_barrier();
        }
        if (!__any(big)) break;
    }

    // ---- epilogue: O = U diag(w) U^T, w = log(lambda) ----
    float nrm2;
    {
        f32x2 a0 = {0.f,0.f}, a1 = {0.f,0.f}, a2 = {0.f,0.f}, a3 = {0.f,0.f};
#pragma unroll
        for (int i = 0; i < 32; i += 4) {
            a0 = __builtin_elementwise_fma(fv[i+0], fv[i+0], a0);
            a1 = __builtin_elementwise_fma(fv[i+1], fv[i+1], a1);
            a2 = __builtin_elementwise_fma(fv[i+2], fv[i+2], a2);
            a3 = __builtin_elementwise_fma(fv[i+3], fv[i+3], a3);
        }
        const f32x2 at = (a0 + a1) + (a2 + a3);
        nrm2 = at.x + at.y;
    }
    const float wk  = 0.5f * logf(nrm2);   // log(||f||) = log(lambda)
    const float inv = rsqrtf(nrm2);

#pragma unroll
    for (int i = 0; i < 16; ++i) {
        myrow[i] = float4{fv[2*i+0].x * inv, fv[2*i+0].y * inv,
                          fv[2*i+1].x * inv, fv[2*i+1].y * inv};  // row lane = u_lane
    }
    wlds[wave][lane] = wk;
    __syncthreads();

    // each lane computes an 8x8 tile of O; O[a][c] = sum_k w_k * U[k][a] * U[k][c]
    const int la = lane >> 3, lb = lane & 7;
    float acc[8][8];
#pragma unroll
    for (int r0 = 0; r0 < 8; ++r0)
#pragma unroll
        for (int c0 = 0; c0 < 8; ++c0) acc[r0][c0] = 0.f;

    const float* wv = wlds[wave];
#pragma unroll 4
    for (int k = 0; k < 64; ++k) {
        const float wkk = wv[k];
        const float* row = T + k * TSTRIDE;
        const float4 p0 = *reinterpret_cast<const float4*>(row + la * 8);
        const float4 p1 = *reinterpret_cast<const float4*>(row + la * 8 + 4);
        const float4 u0 = *reinterpret_cast<const float4*>(row + lb * 8);
        const float4 u1 = *reinterpret_cast<const float4*>(row + lb * 8 + 4);
        const float pr[8] = { p0.x*wkk, p0.y*wkk, p0.z*wkk, p0.w*wkk,
                              p1.x*wkk, p1.y*wkk, p1.z*wkk, p1.w*wkk };
        const float uc[8] = { u0.x, u0.y, u0.z, u0.w, u1.x, u1.y, u1.z, u1.w };
#pragma unroll
        for (int r0 = 0; r0 < 8; ++r0)
#pragma unroll
            for (int c0 = 0; c0 < 8; ++c0)
                acc[r0][c0] = fmaf(pr[r0], uc[c0], acc[r0][c0]);
    }

#pragma unroll
    for (int r0 = 0; r0 < 8; ++r0) {
        float* dst = Ob + (la * 8 + r0) * 64 + lb * 8;
        float4 o0 = { acc[r0][0], acc[r0][1], acc[r0][2], acc[r0][3] };
        float4 o1 = { acc[r0][4], acc[r0][5], acc[r0][6], acc[r0][7] };
        reinterpret_cast<float4*>(dst)[0] = o0;
        reinterpret_cast<float4*>(dst)[1] = o1;
    }
}

extern "C" void kernel_launch(void* const* d_in, const int* in_sizes, int n_in,
                              void* d_out, int out_size, void* d_ws, size_t ws_size,
                              hipStream_t stream)
{
    const float* Xp = (const float*)d_in[0];
    float* Op = (float*)d_out;
    const int B = in_sizes[0] / 4096;                 // 8192
    const int grid = (B + NMAT_PER_BLOCK - 1) / NMAT_PER_BLOCK;  // 2048
    logeig_kernel<<<grid, 256, 0, stream>>>(Xp, Op, B);
}

// Round 5
// 3141.389 us; speedup vs baseline: 1.3226x; 1.0192x over previous
//
#include <hip/hip_runtime.h>
#include <cmath>

// Batched log(SPD 64x64), one-sided Jacobi, LDS-resident columns.
// ONE 64-thread block per matrix (per-matrix convergence exit frees the CU
// slot immediately; ~9 blocks/CU vs 8 waves before).
// Tangent-form rotations with deferred column scale:
//   f_true = rho * fv;  rotation applies fv <- fv - alpha*tv (1 FMA/elem),
//   rho <- rho*c.  All convergence tests use scale-free |apq|/sqrt(app*aqq).
// Tolerances loosened to fit the error budget (6.6e-2): rotate above 1e-4,
// exit sweep-max below 5e-4 (adds ~ 8*5e-4 = 4e-3 to output error).

#define MAXSWEEP 16
#define JTOL 1e-4f
#define XTOL 5e-4f
#define TSTRIDE 68  // floats = 17 float4s (odd) -> conflict-free b128 pattern

typedef float f32x2 __attribute__((ext_vector_type(2)));

__global__ __launch_bounds__(64, 4)
void logeig_kernel(const float* __restrict__ X, float* __restrict__ Out, int B)
{
    const int lane = threadIdx.x & 63;
    const long b = blockIdx.x;

    __shared__ float T[64 * TSTRIDE];
    __shared__ float wlds[64];

    const float* Xb = X + b * 4096;
    float*       Ob = Out + b * 4096;
    float4*      myrow = reinterpret_cast<float4*>(T + lane * TSTRIDE);

    // Column `lane` of X == row `lane` (symmetric) -> contiguous load.
    f32x2 fv[32];
#pragma unroll
    for (int i = 0; i < 16; ++i) {
        const float4 v = reinterpret_cast<const float4*>(Xb + lane * 64)[i];
        fv[2*i+0] = f32x2{v.x, v.y};
        fv[2*i+1] = f32x2{v.z, v.w};
        myrow[i] = v;                       // mirror (unscaled) column into LDS
    }
    __builtin_amdgcn_wave_barrier();

    // unscaled squared column norm (tracked incrementally) + true scale rho
    float app;
    {
        f32x2 a0 = {0.f,0.f}, a1 = {0.f,0.f}, a2 = {0.f,0.f}, a3 = {0.f,0.f};
#pragma unroll
        for (int i = 0; i < 32; i += 4) {
            a0 = __builtin_elementwise_fma(fv[i+0], fv[i+0], a0);
            a1 = __builtin_elementwise_fma(fv[i+1], fv[i+1], a1);
            a2 = __builtin_elementwise_fma(fv[i+2], fv[i+2], a2);
            a3 = __builtin_elementwise_fma(fv[i+3], fv[i+3], a3);
        }
        const f32x2 at = (a0 + a1) + (a2 + a3);
        app = at.x + at.y;
    }
    float rho = 1.0f;

    for (int sweep = 0; sweep < MAXSWEEP; ++sweep) {
        bool big = false;
        for (int r = 1; r < 64; ++r) {
            // XOR tournament: pair (i,j) meets exactly once per sweep at r=i^j
            const int partner = lane ^ r;
            const int pa = partner << 2;

            const float aqq  = __int_as_float(
                __builtin_amdgcn_ds_bpermute(pa, __float_as_int(app)));
            const float rhoq = __int_as_float(
                __builtin_amdgcn_ds_bpermute(pa, __float_as_int(rho)));

            // fetch partner's (unscaled) column: 16 x ds_read_b128
            const float4* pc = reinterpret_cast<const float4*>(T + partner * TSTRIDE);
            f32x2 tv[32];
#pragma unroll
            for (int i = 0; i < 16; ++i) {
                const float4 v = pc[i];
                tv[2*i+0] = f32x2{v.x, v.y};
                tv[2*i+1] = f32x2{v.z, v.w};
            }
#pragma unroll
            for (int i = 0; i < 32; ++i)
                asm volatile("" : "+v"(tv[i]));   // pin (avoid re-read)

            // apq: commutative products, identical order on both lanes of the
            // pair -> bit-identical -> identical decisions & angles.
            float apq;
            {
                f32x2 a0 = {0.f,0.f}, a1 = {0.f,0.f}, a2 = {0.f,0.f}, a3 = {0.f,0.f};
#pragma unroll
                for (int i = 0; i < 32; i += 4) {
                    a0 = __builtin_elementwise_fma(fv[i+0], tv[i+0], a0);
                    a1 = __builtin_elementwise_fma(fv[i+1], tv[i+1], a1);
                    a2 = __builtin_elementwise_fma(fv[i+2], tv[i+2], a2);
                    a3 = __builtin_elementwise_fma(fv[i+3], tv[i+3], a3);
                }
                const f32x2 at = (a0 + a1) + (a2 + a3);
                apq = at.x + at.y;
            }

            const float rel = sqrtf(app * aqq);     // scale-free threshold base
            const bool rot = fabsf(apq) > JTOL * rel;
            big = big || (fabsf(apq) > XTOL * rel);

            if (__any(rot)) {
                // canonical orientation: p = min-lane, q = max-lane. All pair-
                // shared quantities built from commutative products of the same
                // floats on both lanes -> bit-identical tau,t0,c0.
                const bool  isp  = lane < partner;
                const float tapp = (rho  * rho ) * app;   // true ||f_p||^2
                const float taqq = (rhoq * rhoq) * aqq;   // true ||f_q||^2
                const float prod = (rho * rhoq) * apq;    // true <f_p,f_q>
                const float App = isp ? tapp : taqq;
                const float Aqq = isp ? taqq : tapp;
                const float tau = (Aqq - App) / (2.f * prod);
                const float t0  = copysignf(1.f, tau) / (fabsf(tau) + sqrtf(fmaf(tau, tau, 1.f)));
                const float c0  = rsqrtf(fmaf(t0, t0, 1.f));
                const float tl  = isp ? t0 : -t0;         // lane's tangent
                // alpha = tl * rho_q/rho  (unscaled update: fv -= alpha*tv)
                const float alpha = rot ? tl * (rhoq * __builtin_amdgcn_rcpf(rho)) : 0.f;

                const f32x2 na2 = {-alpha, -alpha};
#pragma unroll
                for (int i = 0; i < 32; ++i)
                    fv[i] = __builtin_elementwise_fma(na2, tv[i], fv[i]);

                // exact 2x2 identities (guard non-rotating lanes!)
                app = rot ? (app - alpha * apq) * fmaf(t0, t0, 1.f) : app;
                rho = rot ? rho * c0 : rho;

                if (rot) {  // write updated (unscaled) column back
#pragma unroll
                    for (int i = 0; i < 16; ++i)
                        myrow[i] = float4{fv[2*i+0].x, fv[2*i+0].y,
                                          fv[2*i+1].x, fv[2*i+1].y};
                }
            }
            __builtin_amdgcn_wave_barrier();
        }
        if (!__any(big)) break;
    }

    // ---- epilogue: O = U diag(w) U^T ----
    // lambda = rho*sqrt(nrm2_u); U col = fv/sqrt(nrm2_u) (rho cancels).
    float nrm2;
    {
        f32x2 a0 = {0.f,0.f}, a1 = {0.f,0.f}, a2 = {0.f,0.f}, a3 = {0.f,0.f};
#pragma unroll
        for (int i = 0; i < 32; i += 4) {
            a0 = __builtin_elementwise_fma(fv[i+0], fv[i+0], a0);
            a1 = __builtin_elementwise_fma(fv[i+1], fv[i+1], a1);
            a2 = __builtin_elementwise_fma(fv[i+2], fv[i+2], a2);
            a3 = __builtin_elementwise_fma(fv[i+3], fv[i+3], a3);
        }
        const f32x2 at = (a0 + a1) + (a2 + a3);
        nrm2 = at.x + at.y;
    }
    const float wk  = 0.5f * logf((rho * rho) * nrm2);   // log(lambda)
    const float inv = rsqrtf(nrm2);

#pragma unroll
    for (int i = 0; i < 16; ++i)
        myrow[i] = float4{fv[2*i+0].x * inv, fv[2*i+0].y * inv,
                          fv[2*i+1].x * inv, fv[2*i+1].y * inv};  // row lane = u_lane
    wlds[lane] = wk;
    __syncthreads();

    // each lane computes an 8x8 tile of O; O[a][c] = sum_k w_k U[k][a] U[k][c]
    const int la = lane >> 3, lb = lane & 7;
    float acc[8][8];
#pragma unroll
    for (int r0 = 0; r0 < 8; ++r0)
#pragma unroll
        for (int c0 = 0; c0 < 8; ++c0) acc[r0][c0] = 0.f;

#pragma unroll 4
    for (int k = 0; k < 64; ++k) {
        const float wkk = wlds[k];
        const float* row = T + k * TSTRIDE;
        const float4 p0 = *reinterpret_cast<const float4*>(row + la * 8);
        const float4 p1 = *reinterpret_cast<const float4*>(row + la * 8 + 4);
        const float4 u0 = *reinterpret_cast<const float4*>(row + lb * 8);
        const float4 u1 = *reinterpret_cast<const float4*>(row + lb * 8 + 4);
        const float pr[8] = { p0.x*wkk, p0.y*wkk, p0.z*wkk, p0.w*wkk,
                              p1.x*wkk, p1.y*wkk, p1.z*wkk, p1.w*wkk };
        const float uc[8] = { u0.x, u0.y, u0.z, u0.w, u1.x, u1.y, u1.z, u1.w };
#pragma unroll
        for (int r0 = 0; r0 < 8; ++r0)
#pragma unroll
            for (int c0 = 0; c0 < 8; ++c0)
                acc[r0][c0] = fmaf(pr[r0], uc[c0], acc[r0][c0]);
    }

#pragma unroll
    for (int r0 = 0; r0 < 8; ++r0) {
        float* dst = Ob + (la * 8 + r0) * 64 + lb * 8;
        float4 o0 = { acc[r0][0], acc[r0][1], acc[r0][2], acc[r0][3] };
        float4 o1 = { acc[r0][4], acc[r0][5], acc[r0][6], acc[r0][7] };
        reinterpret_cast<float4*>(dst)[0] = o0;
        reinterpret_cast<float4*>(dst)[1] = o1;
    }
}

extern "C" void kernel_launch(void* const* d_in, const int* in_sizes, int n_in,
                              void* d_out, int out_size, void* d_ws, size_t ws_size,
                              hipStream_t stream)
{
    const float* Xp = (const float*)d_in[0];
    float* Op = (float*)d_out;
    const int B = in_sizes[0] / 4096;   // 8192
    logeig_kernel<<<B, 64, 0, stream>>>(Xp, Op, B);
}

// Round 6
// 3044.560 us; speedup vs baseline: 1.3647x; 1.0318x over previous
//
#include <hip/hip_runtime.h>
#include <cmath>

// Batched log(SPD 64x64), one-sided Jacobi, LDS-resident columns.
// One 64-thread block per matrix. Lane k owns column k in registers, mirrored
// in LDS (stride 68 floats -> conflict-free ds_read_b128). Tangent-form
// rotations with deferred column scale rho (1 FMA/elem update).
// DS-issue-bound: ~16 read_b128 + ~0.6*16 write_b128 + 2 bpermute per round.
//
// r6: XTOL 2e-3 (absmax was tolerance-insensitive at 5e-5..5e-4), mid-sweep
// quiet-counter exit (63 consecutive quiet rounds = all pairs verified),
// wlds folded into T padding (17408 B -> 9 blocks/CU), app overflow guard.

#define MAXSWEEP 16
#define JTOL 2e-4f
#define XTOL 2e-3f
#define TSTRIDE 68  // floats = 17 float4s (odd) -> conflict-free b128 pattern

typedef float f32x2 __attribute__((ext_vector_type(2)));

__global__ __launch_bounds__(64, 2)
void logeig_kernel(const float* __restrict__ X, float* __restrict__ Out, int B)
{
    const int lane = threadIdx.x & 63;
    const long b = blockIdx.x;

    __shared__ float T[64 * TSTRIDE];   // row k = column k of F; [64..67] = pad/w

    const float* Xb = X + b * 4096;
    float*       Ob = Out + b * 4096;
    float4*      myrow = reinterpret_cast<float4*>(T + lane * TSTRIDE);

    // Column `lane` of X == row `lane` (symmetric) -> contiguous load.
    f32x2 fv[32];
#pragma unroll
    for (int i = 0; i < 16; ++i) {
        const float4 v = reinterpret_cast<const float4*>(Xb + lane * 64)[i];
        fv[2*i+0] = f32x2{v.x, v.y};
        fv[2*i+1] = f32x2{v.z, v.w};
        myrow[i] = v;                       // mirror (unscaled) column into LDS
    }
    __builtin_amdgcn_wave_barrier();

    // unscaled squared column norm (tracked incrementally) + true scale rho
    float app;
    {
        f32x2 a0 = {0.f,0.f}, a1 = {0.f,0.f}, a2 = {0.f,0.f}, a3 = {0.f,0.f};
#pragma unroll
        for (int i = 0; i < 32; i += 4) {
            a0 = __builtin_elementwise_fma(fv[i+0], fv[i+0], a0);
            a1 = __builtin_elementwise_fma(fv[i+1], fv[i+1], a1);
            a2 = __builtin_elementwise_fma(fv[i+2], fv[i+2], a2);
            a3 = __builtin_elementwise_fma(fv[i+3], fv[i+3], a3);
        }
        const f32x2 at = (a0 + a1) + (a2 + a3);
        app = at.x + at.y;
    }
    float rho = 1.0f;

    int quiet = 0;                          // consecutive rounds, all pairs < XTOL
    for (int sweep = 0; sweep < MAXSWEEP; ++sweep) {
        for (int r = 1; r < 64; ++r) {
            // XOR tournament: pair (i,j) meets exactly once per sweep at r=i^j
            const int partner = lane ^ r;
            const int pa = partner << 2;

            const float aqq  = __int_as_float(
                __builtin_amdgcn_ds_bpermute(pa, __float_as_int(app)));
            const float rhoq = __int_as_float(
                __builtin_amdgcn_ds_bpermute(pa, __float_as_int(rho)));

            // fetch partner's (unscaled) column: 16 x ds_read_b128
            const float4* pc = reinterpret_cast<const float4*>(T + partner * TSTRIDE);
            f32x2 tv[32];
#pragma unroll
            for (int i = 0; i < 16; ++i) {
                const float4 v = pc[i];
                tv[2*i+0] = f32x2{v.x, v.y};
                tv[2*i+1] = f32x2{v.z, v.w};
            }
#pragma unroll
            for (int i = 0; i < 32; ++i)
                asm volatile("" : "+v"(tv[i]));   // pin (avoid re-read)

            // apq: commutative products, identical order on both lanes of the
            // pair -> bit-identical -> identical decisions & angles.
            float apq;
            {
                f32x2 a0 = {0.f,0.f}, a1 = {0.f,0.f}, a2 = {0.f,0.f}, a3 = {0.f,0.f};
#pragma unroll
                for (int i = 0; i < 32; i += 4) {
                    a0 = __builtin_elementwise_fma(fv[i+0], tv[i+0], a0);
                    a1 = __builtin_elementwise_fma(fv[i+1], tv[i+1], a1);
                    a2 = __builtin_elementwise_fma(fv[i+2], tv[i+2], a2);
                    a3 = __builtin_elementwise_fma(fv[i+3], tv[i+3], a3);
                }
                const f32x2 at = (a0 + a1) + (a2 + a3);
                apq = at.x + at.y;
            }

            const float rel = sqrtf(app * aqq);     // scale-free threshold base
            const bool rot  = fabsf(apq) > JTOL * rel;
            const bool bigr = __any(fabsf(apq) > XTOL * rel);

            if (__any(rot)) {
                // canonical orientation: p = min-lane, q = max-lane. All pair-
                // shared quantities built from commutative products of the same
                // floats on both lanes -> bit-identical tau,t0,c0.
                const bool  isp  = lane < partner;
                const float tapp = (rho  * rho ) * app;   // true ||f_p||^2
                const float taqq = (rhoq * rhoq) * aqq;   // true ||f_q||^2
                const float prod = (rho * rhoq) * apq;    // true <f_p,f_q>
                const float App = isp ? tapp : taqq;
                const float Aqq = isp ? taqq : tapp;
                const float tau = (Aqq - App) / (2.f * prod);
                const float t0  = copysignf(1.f, tau) / (fabsf(tau) + sqrtf(fmaf(tau, tau, 1.f)));
                const float c0  = rsqrtf(fmaf(t0, t0, 1.f));
                const float tl  = isp ? t0 : -t0;         // lane's tangent
                // alpha = tl * rho_q/rho  (unscaled update: fv -= alpha*tv)
                const float alpha = rot ? tl * (rhoq * __builtin_amdgcn_rcpf(rho)) : 0.f;

                const f32x2 na2 = {-alpha, -alpha};
#pragma unroll
                for (int i = 0; i < 32; ++i)
                    fv[i] = __builtin_elementwise_fma(na2, tv[i], fv[i]);

                // exact 2x2 identities (guard non-rotating lanes!)
                app = rot ? (app - alpha * apq) * fmaf(t0, t0, 1.f) : app;
                rho = rot ? rho * c0 : rho;

                // overflow guard for deferred scaling: renormalize rare columns
                const bool renorm = rot && (app > 1e24f);
                if (__any(renorm)) {
                    const float sc = renorm ? rsqrtf(app) : 1.0f;
                    if (renorm) { rho = rho * (app * sc); app = 1.0f; }
                    const f32x2 sc2 = {sc, sc};
#pragma unroll
                    for (int i = 0; i < 32; ++i) fv[i] = fv[i] * sc2;
                }

                if (rot) {  // write updated (unscaled) column back
#pragma unroll
                    for (int i = 0; i < 16; ++i)
                        myrow[i] = float4{fv[2*i+0].x, fv[2*i+0].y,
                                          fv[2*i+1].x, fv[2*i+1].y};
                }
            }
            __builtin_amdgcn_wave_barrier();

            quiet = bigr ? 0 : quiet + 1;
            if (quiet >= 63) break;   // 63 consecutive quiet rounds = all pairs
        }
        if (quiet >= 63) break;
    }

    // ---- epilogue: O = U diag(w) U^T ----
    // lambda = rho*sqrt(nrm2_u); U col = fv/sqrt(nrm2_u) (rho cancels).
    float nrm2;
    {
        f32x2 a0 = {0.f,0.f}, a1 = {0.f,0.f}, a2 = {0.f,0.f}, a3 = {0.f,0.f};
#pragma unroll
        for (int i = 0; i < 32; i += 4) {
            a0 = __builtin_elementwise_fma(fv[i+0], fv[i+0], a0);
            a1 = __builtin_elementwise_fma(fv[i+1], fv[i+1], a1);
            a2 = __builtin_elementwise_fma(fv[i+2], fv[i+2], a2);
            a3 = __builtin_elementwise_fma(fv[i+3], fv[i+3], a3);
        }
        const f32x2 at = (a0 + a1) + (a2 + a3);
        nrm2 = at.x + at.y;
    }
    const float wk  = 0.5f * logf((rho * rho) * nrm2);   // log(lambda)
    const float inv = rsqrtf(nrm2);

#pragma unroll
    for (int i = 0; i < 16; ++i)
        myrow[i] = float4{fv[2*i+0].x * inv, fv[2*i+0].y * inv,
                          fv[2*i+1].x * inv, fv[2*i+1].y * inv};  // row lane = u_lane
    T[lane * TSTRIDE + 64] = wk;            // w stored in row padding
    __syncthreads();

    // each lane computes an 8x8 tile of O; O[a][c] = sum_k w_k U[k][a] U[k][c]
    const int la = lane >> 3, lb = lane & 7;
    float acc[8][8];
#pragma unroll
    for (int r0 = 0; r0 < 8; ++r0)
#pragma unroll
        for (int c0 = 0; c0 < 8; ++c0) acc[r0][c0] = 0.f;

#pragma unroll 4
    for (int k = 0; k < 64; ++k) {
        const float wkk = T[k * TSTRIDE + 64];
        const float* row = T + k * TSTRIDE;
        const float4 p0 = *reinterpret_cast<const float4*>(row + la * 8);
        const float4 p1 = *reinterpret_cast<const float4*>(row + la * 8 + 4);
        const float4 u0 = *reinterpret_cast<const float4*>(row + lb * 8);
        const float4 u1 = *reinterpret_cast<const float4*>(row + lb * 8 + 4);
        const float pr[8] = { p0.x*wkk, p0.y*wkk, p0.z*wkk, p0.w*wkk,
                              p1.x*wkk, p1.y*wkk, p1.z*wkk, p1.w*wkk };
        const float uc[8] = { u0.x, u0.y, u0.z, u0.w, u1.x, u1.y, u1.z, u1.w };
#pragma unroll
        for (int r0 = 0; r0 < 8; ++r0)
#pragma unroll
            for (int c0 = 0; c0 < 8; ++c0)
                acc[r0][c0] = fmaf(pr[r0], uc[c0], acc[r0][c0]);
    }

#pragma unroll
    for (int r0 = 0; r0 < 8; ++r0) {
        float* dst = Ob + (la * 8 + r0) * 64 + lb * 8;
        float4 o0 = { acc[r0][0], acc[r0][1], acc[r0][2], acc[r0][3] };
        float4 o1 = { acc[r0][4], acc[r0][5], acc[r0][6], acc[r0][7] };
        reinterpret_cast<float4*>(dst)[0] = o0;
        reinterpret_cast<float4*>(dst)[1] = o1;
    }
}

extern "C" void kernel_launch(void* const* d_in, const int* in_sizes, int n_in,
                              void* d_out, int out_size, void* d_ws, size_t ws_size,
                              hipStream_t stream)
{
    const float* Xp = (const float*)d_in[0];
    float* Op = (float*)d_out;
    const int B = in_sizes[0] / 4096;   // 8192
    logeig_kernel<<<B, 64, 0, stream>>>(Xp, Op, B);
}